// Round 9
// baseline (279.999 us; speedup 1.0000x reference)
//
#include <hip/hip_runtime.h>
#include <math.h>

#define B_ 8
#define T_ 256
#define IDIM_ 128
#define ODIM_ 128
#define HDIM_ 512
#define CDIM_ 128
#define NROWS_ (B_*T_)
#define TEMPER_ 5.0f
#define ENERGY_TH_ 100.0f
#define N_ITER_ 4
#define XPAD_ 384   // [0,127) zeros | [127,255) x | [255,384) zeros
#define RPB_ 2      // rows per block
#define WPR_ 4      // waves per row -> 512 threads/block
#define NBLK_ (NROWS_/RPB_)   // 1024 blocks

struct Ws {
  unsigned cnt_y_nz;
  unsigned cnt_rows_nm;
  double partial[NROWS_][N_ITER_];   // per-row per-iter loss (plain stores)
};

// 8 blocks x 256 threads; one row per thread
__global__ __launch_bounds__(256) void k_count(const float* __restrict__ y,
                                               Ws* __restrict__ h) {
  __shared__ unsigned redn[256];
  __shared__ unsigned redr[256];
  const int tid = threadIdx.x;
  const int row = blockIdx.x * 256 + tid;
  const float4* yr = (const float4*)(y + row * ODIM_);
  unsigned c = 0;
  #pragma unroll 8
  for (int i = 0; i < 32; ++i) {
    float4 v = yr[i];
    c += (v.x != 0.f) + (v.y != 0.f) + (v.z != 0.f) + (v.w != 0.f);
  }
  redn[tid] = c;
  redr[tid] = (c > 0u) ? 1u : 0u;
  __syncthreads();
  for (int off = 128; off > 0; off >>= 1) {
    if (tid < off) { redn[tid] += redn[tid + off]; redr[tid] += redr[tid + off]; }
    __syncthreads();
  }
  if (tid == 0) {
    atomicAdd(&h->cnt_y_nz, redn[0]);
    atomicAdd(&h->cnt_rows_nm, redr[0]);
  }
}

__device__ inline float wsum(float p) {
  #pragma unroll
  for (int off = 32; off; off >>= 1) p += __shfl_xor(p, off, 64);
  return p;
}
__device__ inline float wmaxf(float p) {
  #pragma unroll
  for (int off = 32; off; off >>= 1) p = fmaxf(p, __shfl_xor(p, off, 64));
  return p;
}
__device__ inline void pick(float& v, int& i, float v2, int i2) {
  if (v2 > v || (v2 == v && i2 < i)) { v = v2; i = i2; }
}

// ---- radix-select (R2/R6-proven): top-CDIM_ of 512 keys, 256-bin, 4 passes.
__device__ inline void radix_topk(const unsigned* key, unsigned* s_hist,
                                  int l, unsigned& t_out, int& rem_out) {
  unsigned prefix = 0u;
  int rem = CDIM_;
  #pragma unroll
  for (int shift = 24; shift >= 0; shift -= 8) {
    unsigned hi_mask = (shift == 24) ? 0u : (0xffffffffu << (shift + 8));
    #pragma unroll
    for (int i = 0; i < 4; ++i) s_hist[4 * l + i] = 0u;
    __threadfence_block();
    #pragma unroll
    for (int k = 0; k < 8; ++k) {
      if ((key[k] & hi_mask) == (prefix & hi_mask))
        atomicAdd(&s_hist[(key[k] >> shift) & 255u], 1u);
    }
    __threadfence_block();
    unsigned h0 = s_hist[4 * l], h1 = s_hist[4 * l + 1];
    unsigned h2 = s_hist[4 * l + 2], h3 = s_hist[4 * l + 3];
    unsigned sum4 = h0 + h1 + h2 + h3;
    unsigned s = sum4;
    #pragma unroll
    for (int off = 1; off < 64; off <<= 1) {
      unsigned o = __shfl(s, min(l + off, 63), 64);
      s += (l + off < 64) ? o : 0u;
    }
    unsigned exclHigh = s - sum4;
    unsigned suf3 = exclHigh;
    unsigned suf2 = suf3 + h3;
    unsigned suf1 = suf2 + h2;
    unsigned suf0 = suf1 + h1;
    unsigned r = (unsigned)rem;
    unsigned enc = 0xffffffffu;
    if (suf0 < r && suf0 + h0 >= r) enc = (suf0 << 8) | (unsigned)(4 * l + 0);
    if (suf1 < r && suf1 + h1 >= r) enc = (suf1 << 8) | (unsigned)(4 * l + 1);
    if (suf2 < r && suf2 + h2 >= r) enc = (suf2 << 8) | (unsigned)(4 * l + 2);
    if (suf3 < r && suf3 + h3 >= r) enc = (suf3 << 8) | (unsigned)(4 * l + 3);
    #pragma unroll
    for (int off = 32; off; off >>= 1) {
      unsigned o = (unsigned)__shfl_xor((int)enc, off, 64);
      enc = (o < enc) ? o : enc;
    }
    rem -= (int)(enc >> 8);
    prefix |= (enc & 255u) << shift;
  }
  t_out = prefix;
  rem_out = rem;
}

__global__ __launch_bounds__(512, 8) void k_main(
    const float* __restrict__ gx, const float* __restrict__ gy,
    const float* __restrict__ enc_w, const float* __restrict__ enc_b,
    const float* __restrict__ dec_w, const float* __restrict__ dec_b,
    Ws* __restrict__ hdr)
{
  const int tid = threadIdx.x;
  const int w   = tid >> 6;     // 0..7 (global wave in block)
  const int l   = tid & 63;
  const int r   = w >> 2;       // row in block (0..1)
  const int ws  = w & 3;        // subwave within row (0..3)
  const int row = blockIdx.x * RPB_ + r;

  __shared__ __align__(16) float s_xpad[RPB_][XPAD_];
  __shared__ __align__(16) float s_y[RPB_][ODIM_];
  __shared__ __align__(16) float s_yatt[RPB_][ODIM_];
  __shared__ __align__(16) float s_h[RPB_][HDIM_];
  __shared__ __align__(16) float s_dot[RPB_][WPR_][256];
  __shared__ __align__(16) float s_nx[RPB_][WPR_][256];
  __shared__ float s_dpart[RPB_][WPR_][ODIM_];
  __shared__ unsigned s_hist[RPB_][256];
  __shared__ unsigned long long s_pack[RPB_][CDIM_];

  const unsigned long long lmask_lt = (l == 0) ? 0ull : ((1ull << l) - 1ull);
  const float* gxr = gx + row * IDIM_;
  const float* gyr = gy + row * ODIM_;

  // ---- init (row-group of 256 threads fills its row's xpad)
  {
    const int local = tid & 255;
    for (int t = local; t < XPAD_; t += 256)
      s_xpad[r][t] = (t >= 127 && t < 255) ? gxr[t - 127] : 0.f;
  }
  float x0 = gxr[l], x1 = gxr[l + 64];   // residual x in registers
  float y0 = gyr[l], y1 = gyr[l + 64];   // residual y in registers
  if (ws == 0) { s_y[r][l] = y0; s_y[r][l + 64] = y1; }
  const bool sq0 = (y0 == 0.f), sq1 = (y1 == 0.f);
  const bool sm_row = (__ballot((!sq0) || (!sq1)) == 0ull);

  const float denom_ll = (float)max(hdr->cnt_y_nz, 1u);
  const float denomh   = (float)max(hdr->cnt_rows_nm * (unsigned)HDIM_, 1u);

  // hoisted per-thread constants
  const int   c_enc = 64 * w + l;            // enc column owned by this thread
  const float eb    = enc_b[c_enc];
  const float db0   = dec_b[l], db1 = dec_b[l + 64];

  unsigned mpack = 0u;     // mprev[k] packed 3 bits each (radix wave only)
  float row_lh = 0.f;
  int theta = 0;

  __syncthreads();

  for (int iter = 0; iter < N_ITER_; ++iter) {
    // ===== P0: sim partials; wave handles j-slice [32*ws, 32*ws+32) =====
    {
      const int jbase = 32 * ws;
      float dot0 = 0, dot1 = 0, dot2 = 0, dot3 = 0;
      float nx0 = 0, nx1 = 0, nx2 = 0, nx3 = 0;
      const int m4 = 4 * l;
      float4 xq0 = *(const float4*)&s_xpad[r][m4 + jbase];
      #pragma unroll
      for (int jb = 0; jb < 8; ++jb) {
        float4 yq  = *(const float4*)&s_y[r][jbase + 4 * jb];
        float4 xq1 = *(const float4*)&s_xpad[r][m4 + jbase + 4 * jb + 4];
        float xa = xq0.x, xb = xq0.y, xc = xq0.z, xd = xq0.w;
        float xe_ = xq1.x, xf = xq1.y, xg = xq1.z;
        dot0 += xa * yq.x; nx0 += xa * xa; dot0 += xb * yq.y; nx0 += xb * xb;
        dot0 += xc * yq.z; nx0 += xc * xc; dot0 += xd * yq.w; nx0 += xd * xd;
        dot1 += xb * yq.x; nx1 += xb * xb; dot1 += xc * yq.y; nx1 += xc * xc;
        dot1 += xd * yq.z; nx1 += xd * xd; dot1 += xe_ * yq.w; nx1 += xe_ * xe_;
        dot2 += xc * yq.x; nx2 += xc * xc; dot2 += xd * yq.y; nx2 += xd * xd;
        dot2 += xe_ * yq.z; nx2 += xe_ * xe_; dot2 += xf * yq.w; nx2 += xf * xf;
        dot3 += xd * yq.x; nx3 += xd * xd; dot3 += xe_ * yq.y; nx3 += xe_ * xe_;
        dot3 += xf * yq.z; nx3 += xf * xf; dot3 += xg * yq.w; nx3 += xg * xg;
        xq0 = xq1;
      }
      float4 dq = {dot0, dot1, dot2, dot3};
      float4 nq = {nx0, nx1, nx2, nx3};
      *(float4*)&s_dot[r][ws][m4] = dq;
      *(float4*)&s_nx[r][ws][m4]  = nq;
    }
    __syncthreads();   // B1

    // ===== P1 (redundant on all 4 row-waves): combine+argmax+softmax =====
    {
      const float normy = sqrtf(wsum(y0 * y0 + y1 * y1));
      float4 d0q = *(const float4*)&s_dot[r][0][4 * l];
      float4 d1q = *(const float4*)&s_dot[r][1][4 * l];
      float4 d2q = *(const float4*)&s_dot[r][2][4 * l];
      float4 d3q = *(const float4*)&s_dot[r][3][4 * l];
      float4 n0q = *(const float4*)&s_nx[r][0][4 * l];
      float4 n1q = *(const float4*)&s_nx[r][1][4 * l];
      float4 n2q = *(const float4*)&s_nx[r][2][4 * l];
      float4 n3q = *(const float4*)&s_nx[r][3][4 * l];
      float dot0 = ((d0q.x + d1q.x) + d2q.x) + d3q.x;
      float dot1 = ((d0q.y + d1q.y) + d2q.y) + d3q.y;
      float dot2 = ((d0q.z + d1q.z) + d2q.z) + d3q.z;
      float dot3 = ((d0q.w + d1q.w) + d2q.w) + d3q.w;
      float nx0 = ((n0q.x + n1q.x) + n2q.x) + n3q.x;
      float nx1 = ((n0q.y + n1q.y) + n2q.y) + n3q.y;
      float nx2 = ((n0q.z + n1q.z) + n2q.z) + n3q.z;
      float nx3 = ((n0q.w + n1q.w) + n2q.w) + n3q.w;
      float den, sv, bestv; int besti;
      den = normy * sqrtf(nx0); sv = (den == 0.f) ? 0.f : dot0 / den;
      bestv = sv; besti = 4 * l;
      den = normy * sqrtf(nx1); sv = (den == 0.f) ? 0.f : dot1 / den;
      pick(bestv, besti, sv, 4 * l + 1);
      den = normy * sqrtf(nx2); sv = (den == 0.f) ? 0.f : dot2 / den;
      pick(bestv, besti, sv, 4 * l + 2);
      if (4 * l + 3 < 255) {
        den = normy * sqrtf(nx3); sv = (den == 0.f) ? 0.f : dot3 / den;
        pick(bestv, besti, sv, 4 * l + 3);
      }
      #pragma unroll
      for (int off = 32; off; off >>= 1) {
        float ov = __shfl_xor(bestv, off, 64);
        int   oi = __shfl_xor(besti, off, 64);
        pick(bestv, besti, ov, oi);
      }
      theta = besti;

      float yal0 = s_xpad[r][theta + l];
      float yal1 = s_xpad[r][theta + l + 64];
      float z0 = yal0 * y0 / TEMPER_;
      float z1 = yal1 * y1 / TEMPER_;
      float zmax = wmaxf(fmaxf(z0, z1));
      float e0 = expf(z0 - zmax), e1 = expf(z1 - zmax);
      float esum = wsum(e0 + e1);
      s_yatt[r][l]      = yal0 * (e0 / esum);   // redundant same-value write
      s_yatt[r][l + 64] = yal1 * (e1 / esum);
    }
    __syncthreads();   // B1b (other row's yatt needed in P2)

    // ===== P2 (all 8 waves): h[both rows] for col c_enc =====
    {
      const float* wp = enc_w + c_enc;
      float a0 = 0.f, a1 = 0.f;
      #pragma unroll 1
      for (int ch = 0; ch < 16; ++ch) {
        float w8[8];
        #pragma unroll
        for (int k = 0; k < 8; ++k) w8[k] = wp[(8 * ch + k) * HDIM_];
        float4 yA0 = *(const float4*)&s_yatt[0][8 * ch];
        float4 yA1 = *(const float4*)&s_yatt[0][8 * ch + 4];
        float4 yB0 = *(const float4*)&s_yatt[1][8 * ch];
        float4 yB1 = *(const float4*)&s_yatt[1][8 * ch + 4];
        a0 += yA0.x * w8[0]; a1 += yB0.x * w8[0];
        a0 += yA0.y * w8[1]; a1 += yB0.y * w8[1];
        a0 += yA0.z * w8[2]; a1 += yB0.z * w8[2];
        a0 += yA0.w * w8[3]; a1 += yB0.w * w8[3];
        a0 += yA1.x * w8[4]; a1 += yB1.x * w8[4];
        a0 += yA1.y * w8[5]; a1 += yB1.y * w8[5];
        a0 += yA1.z * w8[6]; a1 += yB1.z * w8[6];
        a0 += yA1.w * w8[7]; a1 += yB1.w * w8[7];
      }
      s_h[0][c_enc] = a0 + eb;
      s_h[1][c_enc] = a1 + eb;
    }
    __syncthreads();   // B2

    // ===== P3 (one wave per row): hsr radix + pack =====
    if (ws == 0) {
      unsigned* m_hist = s_hist[r];
      unsigned long long* m_pack = s_pack[r];
      float hv[8]; unsigned key[8];
      #pragma unroll
      for (int k = 0; k < 8; ++k) {
        hv[k] = s_h[r][l + 64 * k];
        key[k] = __float_as_uint(hv[k] * hv[k]);
      }
      row_lh = 0.f;
      if (iter > 0) {
        unsigned t0; int rem0;
        radix_topk(key, m_hist, l, t0, rem0);
        int eqbefore = 0; float lacc = 0.f;
        #pragma unroll
        for (int k = 0; k < 8; ++k) {
          bool eq = (key[k] == t0);
          unsigned long long beq = __ballot(eq);
          int rank = eqbefore + __popcll(beq & lmask_lt);
          bool sel0 = (key[k] > t0) || (eq && rank < rem0);
          eqbefore += __popcll(beq);
          int mp = (int)((mpack >> (3 * k)) & 7u);
          if (sel0 && mp > 0 && !sm_row) {
            float d = hv[k] - (1.f - (float)mp);
            lacc += (d * d) / denomh;
          }
        }
        row_lh = wsum(lacc);
        #pragma unroll
        for (int k = 0; k < 8; ++k) {
          if (((mpack >> (3 * k)) & 7u) > 0u) hv[k] = 0.f;
          key[k] = __float_as_uint(hv[k] * hv[k]);
        }
      }
      unsigned t; int rem;
      radix_topk(key, m_hist, l, t, rem);
      int scount = 0, eqbefore = 0;
      #pragma unroll
      for (int k = 0; k < 8; ++k) {
        bool eq = (key[k] == t);
        unsigned long long beq = __ballot(eq);
        int rank = eqbefore + __popcll(beq & lmask_lt);
        bool sel = (key[k] > t) || (eq && rank < rem);
        eqbefore += __popcll(beq);
        unsigned long long mk = __ballot(sel);
        if (sel) {
          int pos = scount + __popcll(mk & lmask_lt);
          m_pack[pos] = (((unsigned long long)__float_as_uint(hv[k])) << 32)
                        | (unsigned)(l + 64 * k);
          mpack += 1u << (3 * k);
        }
        scount += (int)__popcll(mk);
      }
    }
    __syncthreads();   // B3

    // ===== P4: dec partials; wave handles selected chans [32*ws,+32) =====
    {
      float acc0 = 0.f, acc1 = 0.f;
      #pragma unroll 1
      for (int ch = 0; ch < 4; ++ch) {
        float hj[8], w0[8], w1[8];
        #pragma unroll
        for (int j = 0; j < 8; ++j) {
          unsigned long long pk = s_pack[r][32 * ws + 8 * ch + j];
          hj[j] = __uint_as_float((unsigned)(pk >> 32));
          const float* p = dec_w + (unsigned)(pk & 0xffffffffull) * (unsigned)ODIM_;
          w0[j] = p[l];
          w1[j] = p[l + 64];
        }
        #pragma unroll
        for (int j = 0; j < 8; ++j) {
          acc0 += hj[j] * w0[j];
          acc1 += hj[j] * w1[j];
        }
      }
      s_dpart[r][ws][l]      = acc0;
      s_dpart[r][ws][l + 64] = acc1;
    }
    __syncthreads();   // B4

    // ===== P5 (redundant on row's 4 waves): y_ele, loss, residuals =====
    {
      float ye0 = (((s_dpart[r][0][l] + s_dpart[r][1][l]) + s_dpart[r][2][l])
                   + s_dpart[r][3][l]) + db0;
      float ye1 = (((s_dpart[r][0][l+64] + s_dpart[r][1][l+64]) + s_dpart[r][2][l+64])
                   + s_dpart[r][3][l+64]) + db1;

      float tshift  = fabsf((float)theta - 127.f);
      float menergy = tshift + 1.f;
      bool  mmask   = (tshift > ENERGY_TH_);
      float d0 = ye0 - y0, d1 = ye1 - y1;
      float ll0 = sq0 ? 0.f : d0 * d0; ll0 /= denom_ll; ll0 = mmask ? 0.f : ll0; ll0 /= menergy;
      float ll1 = sq1 ? 0.f : d1 * d1; ll1 /= denom_ll; ll1 = mmask ? 0.f : ll1; ll1 /= menergy;
      float row_ll = wsum(ll0 + ll1);
      if (ws == 0 && l == 0)
        hdr->partial[row][iter] = (double)(row_ll + row_lh);   // plain store

      int src0 = l + 127 - theta;
      int src1 = l + 64 + 127 - theta;
      float xe0 = (src0 >= 0 && src0 < ODIM_) ? s_yatt[r][src0] : 0.f;
      float xe1 = (src1 >= 0 && src1 < ODIM_) ? s_yatt[r][src1] : 0.f;
      y0 -= ye0; y1 -= ye1;
      x0 -= xe0; x1 -= xe1;
      s_y[r][l] = y0; s_y[r][l + 64] = y1;          // absolute stores,
      s_xpad[r][127 + l] = x0;                       // redundant same-value
      s_xpad[r][127 + 64 + l] = x1;                  // (benign race)
    }
    __syncthreads();   // B5 (sim of next iter reads s_y/s_xpad)
  }
}

__global__ __launch_bounds__(256) void k_finish(const Ws* __restrict__ hdr,
                                                float* __restrict__ out) {
  __shared__ double red[256];
  const int t = threadIdx.x;
  double s = 0.0;
  #pragma unroll
  for (int g = 0; g < 8; ++g) {
    const double* p = &hdr->partial[t + 256 * g][0];
    s += (p[0] + p[1]) + (p[2] + p[3]);
  }
  red[t] = s;
  __syncthreads();
  for (int off = 128; off > 0; off >>= 1) {
    if (t < off) red[t] += red[t + off];
    __syncthreads();
  }
  if (t == 0) out[0] = (float)(red[0] * 0.25);
}

extern "C" void kernel_launch(void* const* d_in, const int* in_sizes, int n_in,
                              void* d_out, int out_size, void* d_ws, size_t ws_size,
                              hipStream_t stream) {
  (void)in_sizes; (void)n_in; (void)out_size; (void)ws_size;
  const float* x     = (const float*)d_in[0];
  const float* y     = (const float*)d_in[1];
  const float* enc_w = (const float*)d_in[2];
  const float* enc_b = (const float*)d_in[3];
  const float* dec_w = (const float*)d_in[4];
  const float* dec_b = (const float*)d_in[5];
  float* out = (float*)d_out;
  Ws* hdr = (Ws*)d_ws;

  hipMemsetAsync(d_ws, 0, 8, stream);   // zero the two counters only
  hipLaunchKernelGGL(k_count,  dim3(NROWS_ / 256), dim3(256), 0, stream, y, hdr);
  hipLaunchKernelGGL(k_main,   dim3(NBLK_), dim3(512), 0, stream,
                     x, y, enc_w, enc_b, dec_w, dec_b, hdr);
  hipLaunchKernelGGL(k_finish, dim3(1), dim3(256), 0, stream, hdr, out);
}

// Round 10
// 127.377 us; speedup vs baseline: 2.1982x; 2.1982x over previous
//
#include <hip/hip_runtime.h>
#include <math.h>

#define B_ 8
#define T_ 256
#define IDIM_ 128
#define ODIM_ 128
#define HDIM_ 512
#define CDIM_ 128
#define NROWS_ (B_*T_)
#define TEMPER_ 5.0f
#define ENERGY_TH_ 100.0f
#define N_ITER_ 4
#define XPAD_ 384   // [0,127) zeros | [127,255) x | [255,384) zeros
#define RPB_ 4      // rows per block, 2 waves each -> 512 threads
#define NBLK_ (NROWS_/RPB_)

struct Ws {
  unsigned cnt_y_nz;
  unsigned cnt_rows_nm;
  double partial[NROWS_][N_ITER_];   // per-row per-iter loss (plain stores)
};

__global__ __launch_bounds__(256) void k_count(const float* __restrict__ y,
                                               Ws* __restrict__ h) {
  __shared__ unsigned redn[256];
  __shared__ unsigned redr[256];
  const int tid = threadIdx.x;
  const int row = blockIdx.x * 256 + tid;
  const float4* yr = (const float4*)(y + row * ODIM_);
  unsigned c = 0;
  #pragma unroll 8
  for (int i = 0; i < 32; ++i) {
    float4 v = yr[i];
    c += (v.x != 0.f) + (v.y != 0.f) + (v.z != 0.f) + (v.w != 0.f);
  }
  redn[tid] = c;
  redr[tid] = (c > 0u) ? 1u : 0u;
  __syncthreads();
  for (int off = 128; off > 0; off >>= 1) {
    if (tid < off) { redn[tid] += redn[tid + off]; redr[tid] += redr[tid + off]; }
    __syncthreads();
  }
  if (tid == 0) {
    atomicAdd(&h->cnt_y_nz, redn[0]);
    atomicAdd(&h->cnt_rows_nm, redr[0]);
  }
}

__device__ inline float wsum(float p) {
  #pragma unroll
  for (int off = 32; off; off >>= 1) p += __shfl_xor(p, off, 64);
  return p;
}
__device__ inline float wmaxf(float p) {
  #pragma unroll
  for (int off = 32; off; off >>= 1) p = fmaxf(p, __shfl_xor(p, off, 64));
  return p;
}
__device__ inline void pick(float& v, int& i, float v2, int i2) {
  if (v2 > v || (v2 == v && i2 < i)) { v = v2; i = i2; }
}

// ---- radix-select (R2/R6-proven): top-CDIM_ of 512 keys, 256-bin, 4 passes.
__device__ inline void radix_topk(const unsigned* key, unsigned* s_hist,
                                  int l, unsigned& t_out, int& rem_out) {
  unsigned prefix = 0u;
  int rem = CDIM_;
  #pragma unroll
  for (int shift = 24; shift >= 0; shift -= 8) {
    unsigned hi_mask = (shift == 24) ? 0u : (0xffffffffu << (shift + 8));
    #pragma unroll
    for (int i = 0; i < 4; ++i) s_hist[4 * l + i] = 0u;
    __threadfence_block();
    #pragma unroll
    for (int k = 0; k < 8; ++k) {
      if ((key[k] & hi_mask) == (prefix & hi_mask))
        atomicAdd(&s_hist[(key[k] >> shift) & 255u], 1u);
    }
    __threadfence_block();
    unsigned h0 = s_hist[4 * l], h1 = s_hist[4 * l + 1];
    unsigned h2 = s_hist[4 * l + 2], h3 = s_hist[4 * l + 3];
    unsigned sum4 = h0 + h1 + h2 + h3;
    unsigned s = sum4;
    #pragma unroll
    for (int off = 1; off < 64; off <<= 1) {
      unsigned o = __shfl(s, min(l + off, 63), 64);
      s += (l + off < 64) ? o : 0u;
    }
    unsigned exclHigh = s - sum4;
    unsigned suf3 = exclHigh;
    unsigned suf2 = suf3 + h3;
    unsigned suf1 = suf2 + h2;
    unsigned suf0 = suf1 + h1;
    unsigned r = (unsigned)rem;
    unsigned enc = 0xffffffffu;
    if (suf0 < r && suf0 + h0 >= r) enc = (suf0 << 8) | (unsigned)(4 * l + 0);
    if (suf1 < r && suf1 + h1 >= r) enc = (suf1 << 8) | (unsigned)(4 * l + 1);
    if (suf2 < r && suf2 + h2 >= r) enc = (suf2 << 8) | (unsigned)(4 * l + 2);
    if (suf3 < r && suf3 + h3 >= r) enc = (suf3 << 8) | (unsigned)(4 * l + 3);
    #pragma unroll
    for (int off = 32; off; off >>= 1) {
      unsigned o = (unsigned)__shfl_xor((int)enc, off, 64);
      enc = (o < enc) ? o : enc;
    }
    rem -= (int)(enc >> 8);
    prefix |= (enc & 255u) << shift;
  }
  t_out = prefix;
  rem_out = rem;
}

__global__ __launch_bounds__(512, 4) void k_main(
    const float* __restrict__ gx, const float* __restrict__ gy,
    const float* __restrict__ enc_w, const float* __restrict__ enc_b,
    const float* __restrict__ dec_w, const float* __restrict__ dec_b,
    Ws* __restrict__ hdr)
{
  const int tid = threadIdx.x;
  const int wid = tid >> 6;     // 0..7
  const int l   = tid & 63;
  const int r   = wid >> 1;     // row-in-block 0..3
  const int sub = wid & 1;      // wave within pair
  const int row = blockIdx.x * RPB_ + r;

  __shared__ __align__(16) float s_xpad[RPB_][XPAD_];
  __shared__ __align__(16) float s_y[RPB_][ODIM_];
  __shared__ __align__(16) float s_yatt[RPB_][ODIM_];
  __shared__ __align__(16) float s_h[RPB_][HDIM_];
  __shared__ __align__(16) float s_dot[RPB_][2][256];
  __shared__ __align__(16) float s_q[RPB_][XPAD_ + 4];   // prefix of xpad^2
  __shared__ float s_dpart[RPB_][2][ODIM_];
  __shared__ unsigned s_hist[RPB_][2][256];
  __shared__ unsigned long long s_pack[RPB_][CDIM_];
  __shared__ unsigned char s_mprev[RPB_][HDIM_];

  float* m_xpad = s_xpad[r];
  float* m_y    = s_y[r];
  float* m_q    = s_q[r];
  unsigned* m_hist = s_hist[r][sub];
  unsigned long long* m_pack = s_pack[r];

  const unsigned long long lmask_lt = (l == 0) ? 0ull : ((1ull << l) - 1ull);
  const float* gxr = gx + row * IDIM_;
  const float* gyr = gy + row * ODIM_;

  // init
  {
    const int local = tid & 127;
    for (int t = local; t < XPAD_; t += 128)
      m_xpad[t] = (t >= 127 && t < 255) ? gxr[t - 127] : 0.f;
  }
  ((int*)s_mprev)[tid] = 0;   // zero 2048 bytes of mprev
  float y0 = 0.f, y1 = 0.f;
  bool sq0 = false, sq1 = false, sm_row = false;
  if (sub == 0) {
    y0 = gyr[l]; y1 = gyr[l + 64];
    m_y[l] = y0; m_y[l + 64] = y1;
    sq0 = (y0 == 0.f); sq1 = (y1 == 0.f);
    sm_row = (__ballot((!sq0) || (!sq1)) == 0ull);
  }
  const float denom_ll = (float)max(hdr->cnt_y_nz, 1u);
  const float denomh   = (float)max(hdr->cnt_rows_nm * (unsigned)HDIM_, 1u);

  // hoisted constants
  const float eb  = enc_b[tid];          // enc column c = tid
  const float db0 = dec_b[l], db1 = dec_b[l + 64];

  int theta = 0;
  float row_lh = 0.f;

  __syncthreads();

  for (int iter = 0; iter < N_ITER_; ++iter) {
    // ===== P0: dot partials (each wave: half j-range); sub1 also Q-scan =====
    {
      const int jbase = 64 * sub;
      float dot0 = 0, dot1 = 0, dot2 = 0, dot3 = 0;
      const int m4 = 4 * l;
      float4 xq0 = *(const float4*)&m_xpad[m4 + jbase];
      #pragma unroll 4
      for (int jb = 0; jb < 16; ++jb) {
        float4 yq  = *(const float4*)&m_y[jbase + 4 * jb];
        float4 xq1 = *(const float4*)&m_xpad[m4 + jbase + 4 * jb + 4];
        float xa = xq0.x, xb = xq0.y, xc = xq0.z, xd = xq0.w;
        float xe_ = xq1.x, xf = xq1.y, xg = xq1.z;
        dot0 += xa * yq.x; dot0 += xb * yq.y; dot0 += xc * yq.z; dot0 += xd * yq.w;
        dot1 += xb * yq.x; dot1 += xc * yq.y; dot1 += xd * yq.z; dot1 += xe_ * yq.w;
        dot2 += xc * yq.x; dot2 += xd * yq.y; dot2 += xe_ * yq.z; dot2 += xf * yq.w;
        dot3 += xd * yq.x; dot3 += xe_ * yq.y; dot3 += xf * yq.z; dot3 += xg * yq.w;
        xq0 = xq1;
      }
      float4 dq = {dot0, dot1, dot2, dot3};
      *(float4*)&s_dot[r][sub][m4] = dq;

      if (sub == 1) {
        // prefix scan of xpad^2 -> Q[0..384]; lane l owns t = 6l..6l+5
        float x6[6];
        #pragma unroll
        for (int k = 0; k < 6; ++k) x6[k] = m_xpad[6 * l + k];
        float pp1 = x6[0] * x6[0];
        float pp2 = pp1 + x6[1] * x6[1];
        float pp3 = pp2 + x6[2] * x6[2];
        float pp4 = pp3 + x6[3] * x6[3];
        float pp5 = pp4 + x6[4] * x6[4];
        float pp6 = pp5 + x6[5] * x6[5];
        float s = pp6;
        #pragma unroll
        for (int off = 1; off < 64; off <<= 1) {
          float o = __shfl_up(s, off, 64);
          if (l >= off) s += o;
        }
        float excl = s - pp6;
        m_q[6 * l + 0] = excl;
        m_q[6 * l + 1] = excl + pp1;
        m_q[6 * l + 2] = excl + pp2;
        m_q[6 * l + 3] = excl + pp3;
        m_q[6 * l + 4] = excl + pp4;
        m_q[6 * l + 5] = excl + pp5;
        if (l == 63) m_q[384] = excl + pp6;
      }
    }
    __syncthreads();   // B1

    // ===== P1 (sub0): combine + nx from Q + argmax + softmax =====
    if (sub == 0) {
      const float normy = sqrtf(wsum(y0 * y0 + y1 * y1));
      float4 dA = *(const float4*)&s_dot[r][0][4 * l];
      float4 dB = *(const float4*)&s_dot[r][1][4 * l];
      float4 qLo = *(const float4*)&m_q[4 * l];
      float4 qHi = *(const float4*)&m_q[4 * l + 128];
      float dot0 = dA.x + dB.x, dot1 = dA.y + dB.y;
      float dot2 = dA.z + dB.z, dot3 = dA.w + dB.w;
      float nx0 = qHi.x - qLo.x, nx1 = qHi.y - qLo.y;
      float nx2 = qHi.z - qLo.z, nx3 = qHi.w - qLo.w;
      float den, sv, bestv; int besti;
      den = normy * sqrtf(nx0); sv = (den == 0.f) ? 0.f : dot0 / den;
      bestv = sv; besti = 4 * l;
      den = normy * sqrtf(nx1); sv = (den == 0.f) ? 0.f : dot1 / den;
      pick(bestv, besti, sv, 4 * l + 1);
      den = normy * sqrtf(nx2); sv = (den == 0.f) ? 0.f : dot2 / den;
      pick(bestv, besti, sv, 4 * l + 2);
      if (4 * l + 3 < 255) {
        den = normy * sqrtf(nx3); sv = (den == 0.f) ? 0.f : dot3 / den;
        pick(bestv, besti, sv, 4 * l + 3);
      }
      #pragma unroll
      for (int off = 32; off; off >>= 1) {
        float ov = __shfl_xor(bestv, off, 64);
        int   oi = __shfl_xor(besti, off, 64);
        pick(bestv, besti, ov, oi);
      }
      theta = besti;

      float yal0 = m_xpad[theta + l];
      float yal1 = m_xpad[theta + l + 64];
      float z0 = yal0 * y0 / TEMPER_;
      float z1 = yal1 * y1 / TEMPER_;
      float zmax = wmaxf(fmaxf(z0, z1));
      float e0 = expf(z0 - zmax), e1 = expf(z1 - zmax);
      float esum = wsum(e0 + e1);
      s_yatt[r][l]      = yal0 * (e0 / esum);
      s_yatt[r][l + 64] = yal1 * (e1 / esum);
    }
    __syncthreads();   // B2

    // ===== P2 (all 512): h[r'] col c=tid, 16-deep weight chunks =====
    {
      const float* wp = enc_w + tid;
      float a0 = 0.f, a1 = 0.f, a2 = 0.f, a3 = 0.f;
      #pragma unroll 1
      for (int ch = 0; ch < 8; ++ch) {
        float w[16];
        #pragma unroll
        for (int k = 0; k < 16; ++k) w[k] = wp[(16 * ch + k) * HDIM_];
        #pragma unroll
        for (int q = 0; q < 4; ++q) {
          float4 ya0q = *(const float4*)&s_yatt[0][16 * ch + 4 * q];
          float4 ya1q = *(const float4*)&s_yatt[1][16 * ch + 4 * q];
          float4 ya2q = *(const float4*)&s_yatt[2][16 * ch + 4 * q];
          float4 ya3q = *(const float4*)&s_yatt[3][16 * ch + 4 * q];
          #pragma unroll
          for (int u = 0; u < 4; ++u) {
            float wv = w[4 * q + u];
            a0 += ((const float*)&ya0q)[u] * wv;
            a1 += ((const float*)&ya1q)[u] * wv;
            a2 += ((const float*)&ya2q)[u] * wv;
            a3 += ((const float*)&ya3q)[u] * wv;
          }
        }
      }
      s_h[0][tid] = a0 + eb;
      s_h[1][tid] = a1 + eb;
      s_h[2][tid] = a2 + eb;
      s_h[3][tid] = a3 + eb;
    }
    __syncthreads();   // B3

    // ===== P3: DUAL radix — sub0: mask_cur0 + loss; sub1: selection + pack =====
    {
      float hv[8]; unsigned key[8]; int mp[8];
      #pragma unroll
      for (int k = 0; k < 8; ++k) {
        hv[k] = s_h[r][l + 64 * k];
        mp[k] = (int)s_mprev[r][l + 64 * k];
        key[k] = __float_as_uint(hv[k] * hv[k]);
      }
      if (sub == 0) {
        row_lh = 0.f;
        if (iter > 0) {
          unsigned t0; int rem0;
          radix_topk(key, m_hist, l, t0, rem0);
          int eqbefore = 0; float lacc = 0.f;
          #pragma unroll
          for (int k = 0; k < 8; ++k) {
            bool eq = (key[k] == t0);
            unsigned long long beq = __ballot(eq);
            int rank = eqbefore + __popcll(beq & lmask_lt);
            bool sel0 = (key[k] > t0) || (eq && rank < rem0);
            eqbefore += __popcll(beq);
            if (sel0 && mp[k] > 0 && !sm_row) {
              float d = hv[k] - (1.f - (float)mp[k]);
              lacc += (d * d) / denomh;
            }
          }
          row_lh = wsum(lacc);
        }
      } else {
        if (iter > 0) {
          #pragma unroll
          for (int k = 0; k < 8; ++k) {
            if (mp[k] > 0) hv[k] = 0.f;
            key[k] = __float_as_uint(hv[k] * hv[k]);
          }
        }
        unsigned t; int rem;
        radix_topk(key, m_hist, l, t, rem);
        int scount = 0, eqbefore = 0;
        #pragma unroll
        for (int k = 0; k < 8; ++k) {
          bool eq = (key[k] == t);
          unsigned long long beq = __ballot(eq);
          int rank = eqbefore + __popcll(beq & lmask_lt);
          bool sel = (key[k] > t) || (eq && rank < rem);
          eqbefore += __popcll(beq);
          unsigned long long mk = __ballot(sel);
          if (sel) {
            int pos = scount + __popcll(mk & lmask_lt);
            m_pack[pos] = (((unsigned long long)__float_as_uint(hv[k])) << 32)
                          | (unsigned)(l + 64 * k);
            s_mprev[r][l + 64 * k] = (unsigned char)(mp[k] + 1);
          }
          scount += (int)__popcll(mk);
        }
      }
    }
    __syncthreads();   // B4

    // ===== P4: dec partials; each wave 64 selected chans, 16-deep =====
    {
      float acc0 = 0.f, acc1 = 0.f;
      #pragma unroll 1
      for (int ch = 0; ch < 4; ++ch) {
        float hj[16], w0[16], w1[16];
        #pragma unroll
        for (int j = 0; j < 16; ++j) {
          unsigned long long pk = m_pack[64 * sub + 16 * ch + j];
          hj[j] = __uint_as_float((unsigned)(pk >> 32));
          const float* p = dec_w + (unsigned)(pk & 0xffffffffull) * (unsigned)ODIM_;
          w0[j] = p[l];
          w1[j] = p[l + 64];
        }
        #pragma unroll
        for (int j = 0; j < 16; ++j) {
          acc0 += hj[j] * w0[j];
          acc1 += hj[j] * w1[j];
        }
      }
      s_dpart[r][sub][l]      = acc0;
      s_dpart[r][sub][l + 64] = acc1;
    }
    __syncthreads();   // B5

    // ===== P5 (sub0): y_ele, loss, residuals =====
    if (sub == 0) {
      float ye0 = (s_dpart[r][0][l]      + s_dpart[r][1][l])      + db0;
      float ye1 = (s_dpart[r][0][l + 64] + s_dpart[r][1][l + 64]) + db1;

      float tshift  = fabsf((float)theta - 127.f);
      float menergy = tshift + 1.f;
      bool  mmask   = (tshift > ENERGY_TH_);
      float d0 = ye0 - y0, d1 = ye1 - y1;
      float ll0 = sq0 ? 0.f : d0 * d0; ll0 /= denom_ll; ll0 = mmask ? 0.f : ll0; ll0 /= menergy;
      float ll1 = sq1 ? 0.f : d1 * d1; ll1 /= denom_ll; ll1 = mmask ? 0.f : ll1; ll1 /= menergy;
      float row_ll = wsum(ll0 + ll1);
      if (l == 0) hdr->partial[row][iter] = (double)(row_ll + row_lh);

      int src0 = l + 127 - theta;
      int src1 = l + 64 + 127 - theta;
      float xe0 = (src0 >= 0 && src0 < ODIM_) ? s_yatt[r][src0] : 0.f;
      float xe1 = (src1 >= 0 && src1 < ODIM_) ? s_yatt[r][src1] : 0.f;
      y0 -= ye0; y1 -= ye1;
      m_y[l] = y0; m_y[l + 64] = y1;
      m_xpad[127 + l]      -= xe0;
      m_xpad[127 + 64 + l] -= xe1;
    }
    __syncthreads();   // B6
  }
}

__global__ __launch_bounds__(256) void k_finish(const Ws* __restrict__ hdr,
                                                float* __restrict__ out) {
  __shared__ double red[256];
  const int t = threadIdx.x;
  double s = 0.0;
  #pragma unroll
  for (int g = 0; g < 8; ++g) {
    const double* p = &hdr->partial[t + 256 * g][0];
    s += (p[0] + p[1]) + (p[2] + p[3]);
  }
  red[t] = s;
  __syncthreads();
  for (int off = 128; off > 0; off >>= 1) {
    if (t < off) red[t] += red[t + off];
    __syncthreads();
  }
  if (t == 0) out[0] = (float)(red[0] * 0.25);
}

extern "C" void kernel_launch(void* const* d_in, const int* in_sizes, int n_in,
                              void* d_out, int out_size, void* d_ws, size_t ws_size,
                              hipStream_t stream) {
  (void)in_sizes; (void)n_in; (void)out_size; (void)ws_size;
  const float* x     = (const float*)d_in[0];
  const float* y     = (const float*)d_in[1];
  const float* enc_w = (const float*)d_in[2];
  const float* enc_b = (const float*)d_in[3];
  const float* dec_w = (const float*)d_in[4];
  const float* dec_b = (const float*)d_in[5];
  float* out = (float*)d_out;
  Ws* hdr = (Ws*)d_ws;

  hipMemsetAsync(d_ws, 0, 8, stream);   // zero the two counters only
  hipLaunchKernelGGL(k_count,  dim3(NROWS_ / 256), dim3(256), 0, stream, y, hdr);
  hipLaunchKernelGGL(k_main,   dim3(NBLK_), dim3(512), 0, stream,
                     x, y, enc_w, enc_b, dec_w, dec_b, hdr);
  hipLaunchKernelGGL(k_finish, dim3(1), dim3(256), 0, stream, hdr, out);
}